// Round 3
// baseline (4145.616 us; speedup 1.0000x reference)
//
#include <hip/hip_runtime.h>
#include <math.h>

#define TT 50
#define MM 128
#define PP 128
#define FF 64
#define NB 4
#define NTHR 1024
#define BN_EPS 1e-5f

__device__ __forceinline__ float fsig(float x)  { return 1.0f / (1.0f + __expf(-x)); }
__device__ __forceinline__ float ftanh(float x) { return 1.0f - 2.0f / (__expf(2.0f * x) + 1.0f); }

__device__ __forceinline__ float dot4(float4 a, float4 b) {
    return a.x * b.x + a.y * b.y + a.z * b.z + a.w * b.w;
}

__global__ __launch_bounds__(NTHR, 4) void decoder_kernel(
    const float* __restrict__ X,      // (B,T,M)
    const float* __restrict__ yprev,  // (B,T,F)
    const float* __restrict__ w1,     // (128,384)  [w1_d | w1_c | w1_x]
    const float* __restrict__ b1,
    const float* __restrict__ w2,     // (1,128)
    const float* __restrict__ b2,
    const float* __restrict__ fcw,    // (64,192)
    const float* __restrict__ fcb,
    const float* __restrict__ bng,
    const float* __restrict__ bnb,
    const float* __restrict__ bnm,
    const float* __restrict__ bnv,
    const float* __restrict__ wih0,   // (512,64)
    const float* __restrict__ whh0,   // (512,128)
    const float* __restrict__ bih0,
    const float* __restrict__ bhh0,
    const float* __restrict__ wih1,   // (512,128)
    const float* __restrict__ whh1,   // (512,128)
    const float* __restrict__ bih1,
    const float* __restrict__ bhh1,
    const float* __restrict__ fcfw,   // (64,256)
    const float* __restrict__ fcfb,
    float* __restrict__ out)          // (B,64)
{
    __shared__ __align__(16) float Xs[NB][TT][MM + 4];     // 105,600 B (pad 132: odd/4 -> conflict-free)
    __shared__ __align__(16) float sp[NB][MM + 4];
    __shared__ __align__(16) float h0s[2][NB][PP + 4];
    __shared__ __align__(16) float h1s[2][NB][PP + 4];
    __shared__ __align__(16) float c0s[NB][PP + 4], c1s[NB][PP + 4];
    __shared__ __align__(16) float ctxs[NB][MM + 4];
    __shared__ __align__(16) float yts[NB][FF + 4], ytils[NB][FF + 4];
    __shared__ float scs[NB][68];
    __shared__ float w2s[MM];

    const int tid = threadIdx.x;
    const int b0 = blockIdx.x * NB;

    // ---- prologue: X tile -> LDS ----
    for (int i4 = tid; i4 < NB * TT * 32; i4 += NTHR) {
        int bb = i4 / (TT * 32);
        int r  = i4 % (TT * 32);
        float4 v = ((const float4*)(X + (size_t)(b0 + bb) * TT * MM))[r];
        *(float4*)&Xs[bb][r >> 5][(r & 31) * 4] = v;
    }
    for (int i = tid; i < NB * (PP + 4); i += NTHR) {
        int bb = i / (PP + 4), k = i % (PP + 4);
        h0s[0][bb][k] = 0.f; h0s[1][bb][k] = 0.f;
        h1s[0][bb][k] = 0.f; h1s[1][bb][k] = 0.f;
        c0s[bb][k] = 0.f;    c1s[bb][k] = 0.f;
    }
    if (tid < MM) w2s[tid] = w2[tid];
    __syncthreads();

    // ================= per-phase thread mappings (all ts-invariant) =================
    // A: row=tid>>3, bbA=(tid>>1)&3, half=tid&1
    const int rowA = tid >> 3, bbA = (tid >> 1) & 3, halfA = tid & 1;
    const float b1v = b1[rowA];
    // B: bq=tid>>8, rr=tid&255 -> own if rr<200, tq=rr>>2, qq=rr&3
    const int bq = tid >> 8, rr = tid & 255;
    const bool own = rr < 4 * TT;
    const int tq = rr >> 2, qq = rr & 3;
    // D: bbD=tid>>8, mD=(tid>>1)&127, thD=tid&1
    const int bbD = tid >> 8, mD = (tid >> 1) & 127, thD = tid & 1;
    // E/out: fE=tid>>4, bbE=(tid>>2)&3, ksE=tid&3
    const int fE = tid >> 4, bbE = (tid >> 2) & 3, ksE = tid & 3;
    const float fck1 = rsqrtf(bnv[fE] + BN_EPS) * bng[fE];
    const float fck0 = (fcb[fE] - bnm[fE]) * fck1 + bnb[fE];
    // F/G: kFG=tid>>3, bbF=(tid>>1)&3, gh=tid&1 ; rows r0=gh*2P+k, r1=gh*2P+P+k
    const int kFG = tid >> 3, bbF = (tid >> 1) & 3, gh = tid & 1;
    const int r0 = gh * 2 * PP + kFG, r1 = gh * 2 * PP + PP + kFG;
    const float bF0a = bih0[r0] + bhh0[r0], bF0b = bih0[r1] + bhh0[r1];
    const float bF1a = bih1[r0] + bhh1[r0], bF1b = bih1[r1] + bhh1[r1];
    const float b2v = b2[0];

    // ---- x_proj in registers: owner (bq,tq,qq) holds xp[n], n = qq*32+0..31 ----
    float xp[32];
    #pragma unroll
    for (int n = 0; n < 32; ++n) xp[n] = 0.f;
    if (own) {
        for (int m4 = 0; m4 < 32; ++m4) {
            float4 xv = *(const float4*)&Xs[bq][tq][m4 * 4];
            #pragma unroll
            for (int n = 0; n < 32; ++n) {
                float4 w = *(const float4*)(w1 + (size_t)(qq * 32 + n) * 384 + 256 + m4 * 4);
                xp[n] += dot4(xv, w);
            }
        }
    }

    for (int ts = 0; ts < TT; ++ts) {
        const int p = ts & 1;

        // ---- A: state_proj (K-split over wd.h1 / wc.c1) ----
        {
            const float* wbase = w1 + (size_t)rowA * 384 + halfA * 128;
            const float* vec = halfA ? &c1s[bbA][0] : &h1s[p][bbA][0];
            float a = 0.f;
            #pragma unroll 8
            for (int k4 = 0; k4 < 32; ++k4) {
                float4 w = *(const float4*)(wbase + k4 * 4);
                float4 v = *(const float4*)(vec + k4 * 4);
                a += dot4(w, v);
            }
            a += __shfl_xor(a, 1);
            if (halfA == 0) sp[bbA][rowA] = a + b1v;
        }
        __syncthreads();

        // ---- B: score ----
        if (own) {
            float acc = 0.f;
            #pragma unroll
            for (int n = 0; n < 32; ++n)
                acc += ftanh(xp[n] + sp[bq][qq * 32 + n]) * w2s[qq * 32 + n];
            acc += __shfl_xor(acc, 1);
            acc += __shfl_xor(acc, 2);
            if (qq == 0) scs[bq][tq] = acc + b2v;
        }
        __syncthreads();

        // ---- C: softmax (4 waves) + y_t load ----
        if (tid < 256) {
            int b = tid >> 6, t = tid & 63;
            float v = (t < TT) ? scs[b][t] : -1e30f;
            float mx = v;
            #pragma unroll
            for (int o = 32; o; o >>= 1) mx = fmaxf(mx, __shfl_xor(mx, o));
            float e = (t < TT) ? __expf(v - mx) : 0.f;
            float s = e;
            #pragma unroll
            for (int o = 32; o; o >>= 1) s += __shfl_xor(s, o);
            if (t < TT) scs[b][t] = e / s;
        } else if (tid < 512) {
            int i = tid - 256; int bb = i >> 6, f = i & 63;
            yts[bb][f] = yprev[((size_t)(b0 + bb) * TT + ts) * FF + f];
        }
        __syncthreads();

        // ---- D: context (t-split halves) ----
        {
            float acc = 0.f;
            #pragma unroll
            for (int t = 0; t < 25; ++t) {
                int tt = thD * 25 + t;
                acc += scs[bbD][tt] * Xs[bbD][tt][mD];
            }
            acc += __shfl_xor(acc, 1);
            if (thD == 0) ctxs[bbD][mD] = acc;
        }
        __syncthreads();

        // ---- E: fc + batchnorm (K-split by 4) ----
        {
            const float* wr = fcw + (size_t)fE * 192;
            float acc = 0.f;
            #pragma unroll
            for (int j = 0; j < 8; ++j) {
                int k4 = ksE * 8 + j;
                float4 w = *(const float4*)(wr + k4 * 4);
                float4 cx = *(const float4*)&ctxs[bbE][k4 * 4];
                acc += dot4(w, cx);
            }
            #pragma unroll
            for (int j = 0; j < 4; ++j) {
                int k4 = ksE * 4 + j;
                float4 w = *(const float4*)(wr + 128 + k4 * 4);
                float4 yv = *(const float4*)&yts[bbE][k4 * 4];
                acc += dot4(w, yv);
            }
            acc += __shfl_xor(acc, 1);
            acc += __shfl_xor(acc, 2);
            if (ksE == 0) ytils[bbE][fE] = acc * fck1 + fck0;
        }
        __syncthreads();

        // ---- F: lstm0 (2 gate rows per thread) + update ----
        {
            float a0 = bF0a, a1 = bF0b;
            const float* wi0 = wih0 + (size_t)r0 * FF;
            const float* wi1 = wih0 + (size_t)r1 * FF;
            #pragma unroll 8
            for (int k4 = 0; k4 < 16; ++k4) {
                float4 x = *(const float4*)&ytils[bbF][k4 * 4];
                a0 += dot4(x, *(const float4*)(wi0 + k4 * 4));
                a1 += dot4(x, *(const float4*)(wi1 + k4 * 4));
            }
            const float* wh0 = whh0 + (size_t)r0 * PP;
            const float* wh1 = whh0 + (size_t)r1 * PP;
            #pragma unroll 8
            for (int k4 = 0; k4 < 32; ++k4) {
                float4 h = *(const float4*)&h0s[p][bbF][k4 * 4];
                a0 += dot4(h, *(const float4*)(wh0 + k4 * 4));
                a1 += dot4(h, *(const float4*)(wh1 + k4 * 4));
            }
            float og0 = __shfl_xor(a0, 1);   // partner's (g | i)
            float og1 = __shfl_xor(a1, 1);   // partner's (o | f)
            if (gh == 0) {
                float ii = fsig(a0), ff_ = fsig(a1), gg = ftanh(og0), oo = fsig(og1);
                float cn = ff_ * c0s[bbF][kFG] + ii * gg;
                c0s[bbF][kFG] = cn;
                h0s[p ^ 1][bbF][kFG] = oo * ftanh(cn);
            }
        }
        __syncthreads();

        // ---- G: lstm1 (2 gate rows per thread) + update ----
        {
            float a0 = bF1a, a1 = bF1b;
            const float* wi0 = wih1 + (size_t)r0 * PP;
            const float* wi1 = wih1 + (size_t)r1 * PP;
            const float* wh0 = whh1 + (size_t)r0 * PP;
            const float* wh1 = whh1 + (size_t)r1 * PP;
            #pragma unroll 8
            for (int k4 = 0; k4 < 32; ++k4) {
                float4 x = *(const float4*)&h0s[p ^ 1][bbF][k4 * 4];
                a0 += dot4(x, *(const float4*)(wi0 + k4 * 4));
                a1 += dot4(x, *(const float4*)(wi1 + k4 * 4));
            }
            #pragma unroll 8
            for (int k4 = 0; k4 < 32; ++k4) {
                float4 h = *(const float4*)&h1s[p][bbF][k4 * 4];
                a0 += dot4(h, *(const float4*)(wh0 + k4 * 4));
                a1 += dot4(h, *(const float4*)(wh1 + k4 * 4));
            }
            float og0 = __shfl_xor(a0, 1);
            float og1 = __shfl_xor(a1, 1);
            if (gh == 0) {
                float ii = fsig(a0), ff_ = fsig(a1), gg = ftanh(og0), oo = fsig(og1);
                float cn = ff_ * c1s[bbF][kFG] + ii * gg;
                c1s[bbF][kFG] = cn;
                h1s[p ^ 1][bbF][kFG] = oo * ftanh(cn);
            }
        }
        __syncthreads();
    }

    // ---- y_pred = relu([h1, ctx] @ fcf_w.T + fcf_b); final h1 in h1s[0] (TT even) ----
    {
        const float* wr = fcfw + (size_t)fE * 256;
        float acc = 0.f;
        #pragma unroll
        for (int j = 0; j < 16; ++j) {
            int k4 = ksE * 16 + j;
            float4 w = *(const float4*)(wr + k4 * 4);
            float4 v;
            if (k4 < 32) v = *(const float4*)&h1s[0][bbE][k4 * 4];
            else         v = *(const float4*)&ctxs[bbE][(k4 - 32) * 4];
            acc += dot4(w, v);
        }
        acc += __shfl_xor(acc, 1);
        acc += __shfl_xor(acc, 2);
        if (ksE == 0) out[(size_t)(b0 + bbE) * FF + fE] = fmaxf(acc + fcfb[fE], 0.f);
    }
}

extern "C" void kernel_launch(void* const* d_in, const int* in_sizes, int n_in,
                              void* d_out, int out_size, void* d_ws, size_t ws_size,
                              hipStream_t stream) {
    (void)in_sizes; (void)n_in; (void)d_ws; (void)ws_size; (void)out_size;
    const float* X    = (const float*)d_in[0];
    const float* yp   = (const float*)d_in[1];
    const float* w1   = (const float*)d_in[2];
    const float* b1   = (const float*)d_in[3];
    const float* w2   = (const float*)d_in[4];
    const float* b2   = (const float*)d_in[5];
    const float* fcw  = (const float*)d_in[6];
    const float* fcb  = (const float*)d_in[7];
    const float* bng  = (const float*)d_in[8];
    const float* bnb  = (const float*)d_in[9];
    const float* bnm  = (const float*)d_in[10];
    const float* bnv  = (const float*)d_in[11];
    const float* wih0 = (const float*)d_in[12];
    const float* whh0 = (const float*)d_in[13];
    const float* bih0 = (const float*)d_in[14];
    const float* bhh0 = (const float*)d_in[15];
    const float* wih1 = (const float*)d_in[16];
    const float* whh1 = (const float*)d_in[17];
    const float* bih1 = (const float*)d_in[18];
    const float* bhh1 = (const float*)d_in[19];
    const float* fcfw = (const float*)d_in[20];
    const float* fcfb = (const float*)d_in[21];
    float* out = (float*)d_out;

    decoder_kernel<<<dim3(1024 / NB), dim3(NTHR), 0, stream>>>(
        X, yp, w1, b1, w2, b2, fcw, fcb, bng, bnb, bnm, bnv,
        wih0, whh0, bih0, bhh0, wih1, whh1, bih1, bhh1, fcfw, fcfb, out);
}